// Round 2
// baseline (1047.201 us; speedup 1.0000x reference)
//
#include <hip/hip_runtime.h>

typedef float  f32x4  __attribute__((ext_vector_type(4)));
typedef short  bf16x8 __attribute__((ext_vector_type(8)));
typedef unsigned int   u32;
typedef unsigned short u16;

#define N_NODES 30000
#define VOCABSZ 10000
#define LOG2E 1.442695040888963f

__device__ __forceinline__ float sigm(float x){
  return __builtin_amdgcn_rcpf(1.f + __builtin_amdgcn_exp2f(-LOG2E*x));
}
__device__ __forceinline__ float tanh_(float x){
  return 1.f - 2.f*__builtin_amdgcn_rcpf(1.f + __builtin_amdgcn_exp2f((2.f*LOG2E)*x));
}
__device__ __forceinline__ u16 f2bf(float f){   // round-to-nearest-even bf16
  u32 u = __builtin_bit_cast(u32, f);
  u = u + 0x7fffu + ((u>>16)&1u);
  return (u16)(u>>16);
}
__device__ __forceinline__ float bflo(u32 u){ return __builtin_bit_cast(float, u<<16); }
__device__ __forceinline__ float bfhi(u32 u){ return __builtin_bit_cast(float, u & 0xffff0000u); }

// ---------------------------------------------------------------------------
// W_r = sum_b wcomp[r,b] * basis[b]  -> stored [r][i][o] f32 (GEMM-B layout)
// ---------------------------------------------------------------------------
__global__ __launch_bounds__(256) void wmat_kernel(
    const float* __restrict__ b0, const float* __restrict__ c0,
    const float* __restrict__ b1, const float* __restrict__ c1,
    const float* __restrict__ b2, const float* __restrict__ c2,
    float* __restrict__ W0, float* __restrict__ W1, float* __restrict__ W2)
{
  int id = blockIdx.x*256 + threadIdx.x;
  if (id < 32768){
    int r = id>>12;
    float s = 0.f;
    #pragma unroll
    for (int b=0;b<4;++b) s += c0[r*4+b]*b0[b*4096 + (id&4095)];
    W0[id] = s;
  } else if (id < 65536){
    int k = id - 32768;
    int r = k>>12;
    float s = 0.f;
    #pragma unroll
    for (int b=0;b<4;++b) s += c1[r*4+b]*b1[b*4096 + (k&4095)];
    W1[k] = s;
  } else if (id < 73728){
    int k = id - 65536;
    int r = k>>10;
    float s = 0.f;
    #pragma unroll
    for (int b=0;b<4;++b) s += c2[r*4+b]*b2[b*1024 + (k&1023)];
    W2[k] = s;
  }
}

// ---------------------------------------------------------------------------
// emb_proj[v][j] = emb[v]@w_ih[j] + b_ih[j] + b_hh[j]   (bf16, linear [v][512])
// ---------------------------------------------------------------------------
__global__ __launch_bounds__(256) void embproj_kernel(
    const float* __restrict__ emb, const float* __restrict__ w_ih,
    const float* __restrict__ b_ih, const float* __restrict__ b_hh,
    u16* __restrict__ eproj)
{
  __shared__ float et[64*132];
  __shared__ float wt[32*132];
  const int tid = threadIdx.x;
  const int v0 = blockIdx.x*64;
  const int vq = tid>>4, jq = tid&15;

  for (int idx = tid*4; idx < 64*128; idx += 1024){
    int row = idx>>7, col = idx&127;
    int vr = v0 + row; if (vr > VOCABSZ-1) vr = VOCABSZ-1;
    *(f32x4*)&et[row*132+col] = *(const f32x4*)&emb[vr*128+col];
  }
  for (int jt=0; jt<16; ++jt){
    __syncthreads();
    for (int idx = tid*4; idx < 32*128; idx += 1024){
      int row = idx>>7, col = idx&127;
      *(f32x4*)&wt[row*132+col] = *(const f32x4*)&w_ih[(jt*32+row)*128+col];
    }
    __syncthreads();
    float acc[4][2] = {};
    #pragma unroll 4
    for (int k=0;k<128;++k){
      float w0v = wt[(jq*2+0)*132+k];
      float w1v = wt[(jq*2+1)*132+k];
      #pragma unroll
      for (int a=0;a<4;++a){
        float e = et[(vq*4+a)*132+k];
        acc[a][0] += e*w0v;
        acc[a][1] += e*w1v;
      }
    }
    int jb = jt*32 + jq*2;
    float bi0 = b_ih[jb]   + b_hh[jb];
    float bi1 = b_ih[jb+1] + b_hh[jb+1];
    #pragma unroll
    for (int a=0;a<4;++a){
      int v = v0 + vq*4 + a;
      if (v < VOCABSZ){
        u32 pk = (u32)f2bf(acc[a][0]+bi0) | ((u32)f2bf(acc[a][1]+bi1) << 16);
        *(u32*)&eproj[v*512 + jb] = pk;
      }
    }
  }
}

// ---------------------------------------------------------------------------
// Fused 32-step reverse LSTM + fc epilogue.  64 nodes/block, 8 waves,
// LDS 32KB (2 blocks/CU).  Wave w owns k-slice [16w,16w+16) of all 4 gates;
// w_hh lives in registers (A-frags); h (bf16, swizzled, dbuf LDS) streams.
// Cross-step gather prefetch; h written via v_cvt_pk_bf16_f32 + ds_write_b64.
// ---------------------------------------------------------------------------
__global__ __launch_bounds__(512, 4) void lstm_kernel(
    const int* __restrict__ tok, const u16* __restrict__ eproj,
    const float* __restrict__ w_hh, const float* __restrict__ fc_w,
    const float* __restrict__ fc_b, float* __restrict__ feats)
{
  __shared__ __align__(16) char lds[32768];
  const int tid = threadIdx.x;
  const int wave = tid>>6, lane = tid&63;
  const int c16 = lane&15, g4 = lane>>4;
  const int nb = blockIdx.x*64;

  // persistent w_hh A-fragments: j = g*128 + wave*16 + c16 ; k = kk*32+8*g4+i
  bf16x8 afr[4][4];
  #pragma unroll
  for (int g=0; g<4; ++g){
    const float* wr = w_hh + (g*128 + wave*16 + c16)*128 + g4*8;
    #pragma unroll
    for (int kk=0; kk<4; ++kk){
      f32x4 wa = *(const f32x4*)(wr + kk*32);
      f32x4 wbv = *(const f32x4*)(wr + kk*32 + 4);
      bf16x8 a;
      a[0]=(short)f2bf(wa[0]); a[1]=(short)f2bf(wa[1]);
      a[2]=(short)f2bf(wa[2]); a[3]=(short)f2bf(wa[3]);
      a[4]=(short)f2bf(wbv[0]); a[5]=(short)f2bf(wbv[1]);
      a[6]=(short)f2bf(wbv[2]); a[7]=(short)f2bf(wbv[3]);
      afr[g][kk] = a;
    }
  }
  { // zero h buffer 0
    f32x4 z = {0.f,0.f,0.f,0.f};
    for (int i = tid*16; i < 16384; i += 8192) *(f32x4*)(lds + i) = z;
  }
  const int swz = (c16&7)<<4;
  int rb[4];
  #pragma unroll
  for (int kk=0;kk<4;++kk) rb[kk] = c16*256 + ((kk*64 + g4*16)^swz);
  const int wbB = c16*256 + ((wave*32 + g4*8)^swz);

  float creg[4][4];
  #pragma unroll
  for (int nt=0;nt<4;++nt)
    #pragma unroll
    for (int q=0;q<4;++q) creg[nt][q]=0.f;

  int tokc[4], tokn[4];
  #pragma unroll
  for (int nt=0;nt<4;++nt){
    int node = nb + nt*16 + c16; if (node > N_NODES-1) node = N_NODES-1;
    tokc[nt] = tok[node*32 + 31];           // reversed time: step 0 uses t'=31
    tokn[nt] = tokc[nt];
  }
  __syncthreads();

  uint2 gx[2][4];
  #pragma unroll
  for (int p=0;p<2;++p){
    const u16* ep = eproj + tokc[p]*512 + wave*16 + g4*4;
    #pragma unroll
    for (int g=0; g<4; ++g) gx[p][g] = *(const uint2*)(ep + g*128);
  }

  for (int t=0; t<32; ++t){
    const int bufR = (t&1)<<14, bufW = bufR ^ 16384;
    if (t < 31){
      #pragma unroll
      for (int nt=0;nt<4;++nt){
        int node = nb + nt*16 + c16; if (node > N_NODES-1) node = N_NODES-1;
        tokn[nt] = tok[node*32 + (30 - t)];
      }
    }
    #pragma unroll
    for (int nt=0; nt<4; ++nt){
      f32x4 acc[4];
      #pragma unroll
      for (int g=0; g<4; ++g){        // acc init = gathered gates_x
        uint2 d = gx[nt&1][g];
        acc[g][0]=bflo(d.x); acc[g][1]=bfhi(d.x);
        acc[g][2]=bflo(d.y); acc[g][3]=bfhi(d.y);
      }
      if (nt < 2 || t < 31){          // prefetch 2 tiles ahead (crosses steps)
        int ptok = (nt < 2) ? tokc[nt+2] : tokn[nt-2];
        const u16* ep = eproj + ptok*512 + wave*16 + g4*4;
        #pragma unroll
        for (int g=0; g<4; ++g) gx[nt&1][g] = *(const uint2*)(ep + g*128);
      }
      bf16x8 bfr[4];
      #pragma unroll
      for (int kk=0;kk<4;++kk)
        bfr[kk] = *(const bf16x8*)(lds + bufR + rb[kk] + nt*4096);
      #pragma unroll
      for (int kk=0;kk<4;++kk){
        acc[0] = __builtin_amdgcn_mfma_f32_16x16x32_bf16(afr[0][kk], bfr[kk], acc[0], 0,0,0);
        acc[1] = __builtin_amdgcn_mfma_f32_16x16x32_bf16(afr[1][kk], bfr[kk], acc[1], 0,0,0);
        acc[2] = __builtin_amdgcn_mfma_f32_16x16x32_bf16(afr[2][kk], bfr[kk], acc[2], 0,0,0);
        acc[3] = __builtin_amdgcn_mfma_f32_16x16x32_bf16(afr[3][kk], bfr[kk], acc[3], 0,0,0);
      }
      float hv[4];
      #pragma unroll
      for (int q=0;q<4;++q){          // gates: i,f,g,o
        float zi=acc[0][q], zf=acc[1][q], zg=acc[2][q], zo=acc[3][q];
        float cn = sigm(zf)*creg[nt][q] + sigm(zi)*tanh_(zg);
        creg[nt][q] = cn;
        hv[q] = sigm(zo)*tanh_(cn);
      }
      u32 plo, phi;
      asm("v_cvt_pk_bf16_f32 %0, %1, %2" : "=v"(plo) : "v"(hv[0]), "v"(hv[1]));
      asm("v_cvt_pk_bf16_f32 %0, %1, %2" : "=v"(phi) : "v"(hv[2]), "v"(hv[3]));
      uint2 hw; hw.x = plo; hw.y = phi;
      *(uint2*)(lds + bufW + wbB + nt*4096) = hw;
    }
    #pragma unroll
    for (int nt=0;nt<4;++nt) tokc[nt] = tokn[nt];
    __syncthreads();
  }
  // fc epilogue: final h in buffer 0; wave pair (w2) handles node-tile w2,
  // each half covers 2 of the 4 output tiles.
  const int w2 = wave>>1, half = wave&1;
  f32x4 fca[2];
  #pragma unroll
  for (int oi=0;oi<2;++oi){ fca[oi][0]=0.f; fca[oi][1]=0.f; fca[oi][2]=0.f; fca[oi][3]=0.f; }
  #pragma unroll
  for (int kk=0;kk<4;++kk){
    bf16x8 b = *(const bf16x8*)(lds + rb[kk] + w2*4096);
    #pragma unroll
    for (int oi=0;oi<2;++oi){
      int ot = half*2 + oi;
      const float* fr = fc_w + (ot*16 + c16)*128 + kk*32 + g4*8;
      f32x4 wa = *(const f32x4*)fr;
      f32x4 wbv = *(const f32x4*)(fr+4);
      bf16x8 a;
      a[0]=(short)f2bf(wa[0]); a[1]=(short)f2bf(wa[1]);
      a[2]=(short)f2bf(wa[2]); a[3]=(short)f2bf(wa[3]);
      a[4]=(short)f2bf(wbv[0]); a[5]=(short)f2bf(wbv[1]);
      a[6]=(short)f2bf(wbv[2]); a[7]=(short)f2bf(wbv[3]);
      fca[oi] = __builtin_amdgcn_mfma_f32_16x16x32_bf16(a, b, fca[oi], 0,0,0);
    }
  }
  const int node = nb + w2*16 + c16;
  if (node < N_NODES){
    #pragma unroll
    for (int oi=0;oi<2;++oi)
      #pragma unroll
      for (int q=0;q<4;++q){
        int o = (half*2+oi)*16 + g4*4 + q;
        feats[node*64 + o] = fca[oi][q] + fc_b[o];
      }
  }
}

// ---------------------------------------------------------------------------
// RGCN scatter: agg[dst][rel][:] += h[src][:] * norm      (wave per edge)
// ---------------------------------------------------------------------------
__global__ __launch_bounds__(256) void scatter_kernel(
    const float* __restrict__ h, const int* __restrict__ src,
    const int* __restrict__ dst, const int* __restrict__ rel,
    const float* __restrict__ enorm, float* __restrict__ agg, int n_edges)
{
  const int lane = threadIdx.x&63;
  const int stride = gridDim.x*4;
  for (int e = blockIdx.x*4 + (threadIdx.x>>6); e < n_edges; e += stride){
    int s = src[e], d = dst[e], r = rel[e];
    float m = h[s*64 + lane] * enorm[e];
    unsafeAtomicAdd(agg + (d*8 + r)*64 + lane, m);
  }
}

// ---------------------------------------------------------------------------
// RGCN transform: out[n][o] = (relu?) sum_k agg[n][k] * W[k][o]   (K=512)
// f32 tiled GEMM, 128n x NO per block, 8n x (NO/16) per thread, dbuf k-tiles.
// ---------------------------------------------------------------------------
template<int NO, bool RELU>
__global__ __launch_bounds__(256) void transform_kernel(
    const float* __restrict__ agg, const float* __restrict__ W,
    float* __restrict__ out, int n_nodes)
{
  __shared__ float Ald[2][16][128];
  __shared__ float Bld[2][16][NO];
  const int tid = threadIdx.x;
  const int n0 = blockIdx.x*128;
  const int tx = tid&15, ty = tid>>4;
  constexpr int OC = NO/16;

  const int sn = tid&127;          // staging: node within tile
  const int sc = tid>>7;           // staging: k-chunk 0/1
  int nr = n0 + sn; if (nr > n_nodes-1) nr = n_nodes-1;
  const float* arow = agg + (size_t)nr*512;

  float acc[8][OC];
  #pragma unroll
  for (int i=0;i<8;++i)
    #pragma unroll
    for (int j=0;j<OC;++j) acc[i][j]=0.f;

  { // stage k-tile 0
    f32x4 av0 = *(const f32x4*)(arow + sc*8);
    f32x4 av1 = *(const f32x4*)(arow + sc*8 + 4);
    #pragma unroll
    for (int j=0;j<4;++j){ Ald[0][sc*8+j][sn]=av0[j]; Ald[0][sc*8+4+j][sn]=av1[j]; }
    if (NO == 64){
      f32x4 bv = *(const f32x4*)(W + (tid>>4)*64 + (tid&15)*4);
      *(f32x4*)&Bld[0][tid>>4][(tid&15)*4] = bv;
    } else {
      Bld[0][tid>>4][tid&15] = W[(tid>>4)*16 + (tid&15)];
    }
  }
  __syncthreads();

  for (int kt=0; kt<32; ++kt){
    const int cur = kt&1, nxt = cur^1;
    if (kt < 31){
      const float* ar = arow + (kt+1)*16;
      f32x4 av0 = *(const f32x4*)(ar + sc*8);
      f32x4 av1 = *(const f32x4*)(ar + sc*8 + 4);
      #pragma unroll
      for (int j=0;j<4;++j){ Ald[nxt][sc*8+j][sn]=av0[j]; Ald[nxt][sc*8+4+j][sn]=av1[j]; }
      if (NO == 64){
        f32x4 bv = *(const f32x4*)(W + ((kt+1)*16 + (tid>>4))*64 + (tid&15)*4);
        *(f32x4*)&Bld[nxt][tid>>4][(tid&15)*4] = bv;
      } else {
        Bld[nxt][tid>>4][tid&15] = W[((kt+1)*16 + (tid>>4))*16 + (tid&15)];
      }
    }
    #pragma unroll
    for (int k=0;k<16;++k){
      f32x4 a0 = *(const f32x4*)&Ald[cur][k][ty*8];
      f32x4 a1 = *(const f32x4*)&Ald[cur][k][ty*8+4];
      float bv[OC];
      if (NO == 64){
        f32x4 b4 = *(const f32x4*)&Bld[cur][k][tx*4];
        #pragma unroll
        for (int j=0;j<OC;++j) bv[j] = b4[j];
      } else {
        bv[0] = Bld[cur][k][tx];
      }
      #pragma unroll
      for (int i=0;i<4;++i)
        #pragma unroll
        for (int j=0;j<OC;++j){
          acc[i][j]   += a0[i]*bv[j];
          acc[i+4][j] += a1[i]*bv[j];
        }
    }
    __syncthreads();
  }
  #pragma unroll
  for (int i=0;i<8;++i){
    int n = n0 + ty*8 + i;
    if (n < n_nodes){
      if (NO == 64){
        f32x4 v;
        #pragma unroll
        for (int j=0;j<4;++j){
          float x = acc[i][j];
          v[j] = RELU ? fmaxf(x, 0.f) : x;
        }
        *(f32x4*)(out + (size_t)n*64 + tx*4) = v;
      } else {
        float x = acc[i][0];
        out[(size_t)n*16 + tx] = RELU ? fmaxf(x, 0.f) : x;
      }
    }
  }
}

// ---------------------------------------------------------------------------
extern "C" void kernel_launch(void* const* d_in, const int* in_sizes, int n_in,
                              void* d_out, int out_size, void* d_ws, size_t ws_size,
                              hipStream_t stream)
{
  const int*   tok    = (const int*)  d_in[0];
  const int*   src    = (const int*)  d_in[2];
  const int*   dst    = (const int*)  d_in[3];
  const int*   rel    = (const int*)  d_in[4];
  const float* enorm  = (const float*)d_in[5];
  const float* emb    = (const float*)d_in[6];
  const float* w_ih   = (const float*)d_in[7];
  const float* w_hh   = (const float*)d_in[8];
  const float* b_ih   = (const float*)d_in[9];
  const float* b_hh   = (const float*)d_in[10];
  const float* fc_w   = (const float*)d_in[11];
  const float* fc_b   = (const float*)d_in[12];
  const float* basis0 = (const float*)d_in[13];
  const float* wcomp0 = (const float*)d_in[14];
  const float* basis1 = (const float*)d_in[15];
  const float* wcomp1 = (const float*)d_in[16];
  const float* basis2 = (const float*)d_in[17];
  const float* wcomp2 = (const float*)d_in[18];

  char* ws = (char*)d_ws;
  // agg [0, 61.44M) ; eproj overlaps its head (dead before first memset)
  float* agg   = (float*)(ws);                 // 61,440,000 B
  u16*   eproj = (u16*)  (ws);                 // 10,240,000 B (inside agg)
  float* feats = (float*)(ws + 61440000);      //  7,680,000 B
  float* g1    = (float*)(ws + 69120000);      //  7,680,000 B
  float* g2    = (float*)(ws + 61440000);      //  reuses feats (dead by then)
  float* W0    = (float*)(ws + 76800000);      //    131,072 B
  float* W1    = (float*)(ws + 76931072);      //    131,072 B
  float* W2    = (float*)(ws + 77062144);      //     32,768 B

  wmat_kernel<<<288, 256, 0, stream>>>(basis0, wcomp0, basis1, wcomp1,
                                       basis2, wcomp2, W0, W1, W2);
  embproj_kernel<<<157, 256, 0, stream>>>(emb, w_ih, b_ih, b_hh, eproj);
  lstm_kernel<<<469, 512, 0, stream>>>(tok, eproj, w_hh, fc_w, fc_b, feats);

  // layer 0: feats -> g1 (relu)
  hipMemsetAsync(agg, 0, 61440000, stream);
  scatter_kernel<<<2048, 256, 0, stream>>>(feats, src, dst, rel, enorm, agg, 480000);
  transform_kernel<64, true><<<235, 256, 0, stream>>>(agg, W0, g1, N_NODES);

  // layer 1: g1 -> g2 (relu)
  hipMemsetAsync(agg, 0, 61440000, stream);
  scatter_kernel<<<2048, 256, 0, stream>>>(g1, src, dst, rel, enorm, agg, 480000);
  transform_kernel<64, true><<<235, 256, 0, stream>>>(agg, W1, g2, N_NODES);

  // layer 2: g2 -> out (no activation)
  hipMemsetAsync(agg, 0, 61440000, stream);
  scatter_kernel<<<2048, 256, 0, stream>>>(g2, src, dst, rel, enorm, agg, 480000);
  transform_kernel<16, false><<<235, 256, 0, stream>>>(agg, W2, (float*)d_out, N_NODES);
}

// Round 4
// 736.252 us; speedup vs baseline: 1.4223x; 1.4223x over previous
//
#include <hip/hip_runtime.h>

typedef float  f32x4  __attribute__((ext_vector_type(4)));
typedef short  bf16x8 __attribute__((ext_vector_type(8)));
typedef unsigned int   u32;
typedef unsigned short u16;

#define N_NODES 30000
#define VOCABSZ 10000
#define LOG2E 1.442695040888963f

__device__ __forceinline__ float sigm(float x){
  return __builtin_amdgcn_rcpf(1.f + __builtin_amdgcn_exp2f(-LOG2E*x));
}
__device__ __forceinline__ float tanh_(float x){
  return 1.f - 2.f*__builtin_amdgcn_rcpf(1.f + __builtin_amdgcn_exp2f((2.f*LOG2E)*x));
}
__device__ __forceinline__ u16 f2bf(float f){   // round-to-nearest-even bf16
  u32 u = __builtin_bit_cast(u32, f);
  u = u + 0x7fffu + ((u>>16)&1u);
  return (u16)(u>>16);
}
__device__ __forceinline__ float bflo(u32 u){ return __builtin_bit_cast(float, u<<16); }
__device__ __forceinline__ float bfhi(u32 u){ return __builtin_bit_cast(float, u & 0xffff0000u); }

// ---------------------------------------------------------------------------
// W_r = sum_b wcomp[r,b] * basis[b]  -> stored [r][i][o] f32 (GEMM-B layout)
// ---------------------------------------------------------------------------
__global__ __launch_bounds__(256) void wmat_kernel(
    const float* __restrict__ b0, const float* __restrict__ c0,
    const float* __restrict__ b1, const float* __restrict__ c1,
    const float* __restrict__ b2, const float* __restrict__ c2,
    float* __restrict__ W0, float* __restrict__ W1, float* __restrict__ W2)
{
  int id = blockIdx.x*256 + threadIdx.x;
  if (id < 32768){
    int r = id>>12;
    float s = 0.f;
    #pragma unroll
    for (int b=0;b<4;++b) s += c0[r*4+b]*b0[b*4096 + (id&4095)];
    W0[id] = s;
  } else if (id < 65536){
    int k = id - 32768;
    int r = k>>12;
    float s = 0.f;
    #pragma unroll
    for (int b=0;b<4;++b) s += c1[r*4+b]*b1[b*4096 + (k&4095)];
    W1[k] = s;
  } else if (id < 73728){
    int k = id - 65536;
    int r = k>>10;
    float s = 0.f;
    #pragma unroll
    for (int b=0;b<4;++b) s += c2[r*4+b]*b2[b*1024 + (k&1023)];
    W2[k] = s;
  }
}

// ---------------------------------------------------------------------------
// emb_proj: bf16 table [v][512] in GATHER-FRIENDLY order:
//   original j = g*128 + w*16 + g4*4 + jl  ->  j' = w*64 + g4*16 + jl*4 + g
// so lane (w,c16,g4) reads its 16 values (4 gates x 4 j) as 32 contiguous B.
// ---------------------------------------------------------------------------
__global__ __launch_bounds__(256) void embproj_kernel(
    const float* __restrict__ emb, const float* __restrict__ w_ih,
    const float* __restrict__ b_ih, const float* __restrict__ b_hh,
    u16* __restrict__ eproj)
{
  __shared__ float et[64*132];
  __shared__ float wt[32*132];
  const int tid = threadIdx.x;
  const int v0 = blockIdx.x*64;
  const int vq = tid>>4, jq = tid&15;

  for (int idx = tid*4; idx < 64*128; idx += 1024){
    int row = idx>>7, col = idx&127;
    int vr = v0 + row; if (vr > VOCABSZ-1) vr = VOCABSZ-1;
    *(f32x4*)&et[row*132+col] = *(const f32x4*)&emb[vr*128+col];
  }
  for (int jt=0; jt<16; ++jt){
    __syncthreads();
    for (int idx = tid*4; idx < 32*128; idx += 1024){
      int row = idx>>7, col = idx&127;
      *(f32x4*)&wt[row*132+col] = *(const f32x4*)&w_ih[(jt*32+row)*128+col];
    }
    __syncthreads();
    float acc[4][2] = {};
    #pragma unroll 4
    for (int k=0;k<128;++k){
      float w0v = wt[(jq*2+0)*132+k];
      float w1v = wt[(jq*2+1)*132+k];
      #pragma unroll
      for (int a=0;a<4;++a){
        float e = et[(vq*4+a)*132+k];
        acc[a][0] += e*w0v;
        acc[a][1] += e*w1v;
      }
    }
    int jb = jt*32 + jq*2;
    float bi0 = b_ih[jb]   + b_hh[jb];
    float bi1 = b_ih[jb+1] + b_hh[jb+1];
    // j -> j' mapping (jb even => second value lands at j'+4)
    int g  = jb>>7, rem = jb&127;
    int w  = rem>>4, q4 = (rem>>2)&3, jl = rem&3;
    int jp = w*64 + q4*16 + jl*4 + g;
    #pragma unroll
    for (int a=0;a<4;++a){
      int v = v0 + vq*4 + a;
      if (v < VOCABSZ){
        eproj[v*512 + jp]     = f2bf(acc[a][0]+bi0);
        eproj[v*512 + jp + 4] = f2bf(acc[a][1]+bi1);
      }
    }
  }
}

// ---------------------------------------------------------------------------
// Fused 32-step reverse LSTM + fc epilogue.  128 nodes/block, 8 waves,
// (512,2): 1 block/CU, ~220 VGPR, NO spill.  w_hh A-frags in registers.
// h: bf16, XOR-swizzled, double-buffered 64KB LDS.  Tokens staged in LDS.
// eproj gathers: 2x b128 per (nt), full-line, rolling FULL-STEP prefetch.
// ---------------------------------------------------------------------------
__global__ __launch_bounds__(512, 2) void lstm_kernel(
    const int* __restrict__ tok, const u16* __restrict__ eproj,
    const float* __restrict__ w_hh, const float* __restrict__ fc_w,
    const float* __restrict__ fc_b, float* __restrict__ feats)
{
  __shared__ __align__(16) char lds[65536];
  __shared__ int tokL[128*33];
  const int tid = threadIdx.x;
  const int wave = tid>>6, lane = tid&63;
  const int c16 = lane&15, g4 = lane>>4;
  const int nb = blockIdx.x*128;

  // persistent w_hh A-fragments: j = g*128 + wave*16 + c16 ; k = kk*32+8*g4+i
  bf16x8 afr[4][4];
  #pragma unroll
  for (int g=0; g<4; ++g){
    const float* wr = w_hh + (g*128 + wave*16 + c16)*128 + g4*8;
    #pragma unroll
    for (int kk=0; kk<4; ++kk){
      f32x4 wa = *(const f32x4*)(wr + kk*32);
      f32x4 wbv = *(const f32x4*)(wr + kk*32 + 4);
      bf16x8 a;
      a[0]=(short)f2bf(wa[0]); a[1]=(short)f2bf(wa[1]);
      a[2]=(short)f2bf(wa[2]); a[3]=(short)f2bf(wa[3]);
      a[4]=(short)f2bf(wbv[0]); a[5]=(short)f2bf(wbv[1]);
      a[6]=(short)f2bf(wbv[2]); a[7]=(short)f2bf(wbv[3]);
      afr[g][kk] = a;
    }
  }
  { // zero h buffer 0
    f32x4 z = {0.f,0.f,0.f,0.f};
    for (int i = tid*16; i < 32768; i += 8192) *(f32x4*)(lds + i) = z;
  }
  { // stage all tokens: tokL[n][33] (padded: bank-conflict-free reads)
    int n = tid>>2, t0 = (tid&3)*8;
    int node = nb + n; if (node > N_NODES-1) node = N_NODES-1;
    int4 a = *(const int4*)(tok + node*32 + t0);
    int4 b = *(const int4*)(tok + node*32 + t0 + 4);
    int* dstp = &tokL[n*33 + t0];
    dstp[0]=a.x; dstp[1]=a.y; dstp[2]=a.z; dstp[3]=a.w;
    dstp[4]=b.x; dstp[5]=b.y; dstp[6]=b.z; dstp[7]=b.w;
  }
  const int swz = (c16&7)<<4;
  int rb[4];
  #pragma unroll
  for (int kk=0;kk<4;++kk) rb[kk] = c16*256 + ((kk*64 + g4*16)^swz);
  const int wbB = c16*256 + ((wave*32 + g4*8)^swz);

  float creg[8][4];
  #pragma unroll
  for (int nt=0;nt<8;++nt)
    #pragma unroll
    for (int q=0;q<4;++q) creg[nt][q]=0.f;

  __syncthreads();

  const size_t gbase = (size_t)(wave*128 + g4*32);
  uint4 gxX[8], gxY[8];
  #pragma unroll
  for (int nt=0;nt<8;++nt){                 // initial gathers (t=0, t'=31)
    int ptok = tokL[(nt*16+c16)*33 + 31];
    const char* ep = (const char*)eproj + (size_t)ptok*1024 + gbase;
    gxX[nt] = *(const uint4*)ep;
    gxY[nt] = *(const uint4*)(ep+16);
  }

  for (int t=0; t<32; ++t){
    const int bufR = (t&1)<<15, bufW = bufR ^ 32768;
    int ptk[8];
    if (t < 31){
      #pragma unroll
      for (int nt=0;nt<8;++nt) ptk[nt] = tokL[(nt*16+c16)*33 + 30 - t];
    }
    #pragma unroll
    for (int nt=0; nt<8; ++nt){
      uint4 X = gxX[nt], Y = gxY[nt];
      f32x4 acc[4];
      acc[0][0]=bflo(X.x); acc[1][0]=bfhi(X.x); acc[2][0]=bflo(X.y); acc[3][0]=bfhi(X.y);
      acc[0][1]=bflo(X.z); acc[1][1]=bfhi(X.z); acc[2][1]=bflo(X.w); acc[3][1]=bfhi(X.w);
      acc[0][2]=bflo(Y.x); acc[1][2]=bfhi(Y.x); acc[2][2]=bflo(Y.y); acc[3][2]=bfhi(Y.y);
      acc[0][3]=bflo(Y.z); acc[1][3]=bfhi(Y.z); acc[2][3]=bflo(Y.w); acc[3][3]=bfhi(Y.w);
      if (t < 31){                          // rolling prefetch: next step, same nt
        const char* ep = (const char*)eproj + (size_t)ptk[nt]*1024 + gbase;
        gxX[nt] = *(const uint4*)ep;
        gxY[nt] = *(const uint4*)(ep+16);
      }
      bf16x8 bfr[4];
      #pragma unroll
      for (int kk=0;kk<4;++kk)
        bfr[kk] = *(const bf16x8*)(lds + bufR + rb[kk] + nt*4096);
      #pragma unroll
      for (int kk=0;kk<4;++kk){
        acc[0] = __builtin_amdgcn_mfma_f32_16x16x32_bf16(afr[0][kk], bfr[kk], acc[0], 0,0,0);
        acc[1] = __builtin_amdgcn_mfma_f32_16x16x32_bf16(afr[1][kk], bfr[kk], acc[1], 0,0,0);
        acc[2] = __builtin_amdgcn_mfma_f32_16x16x32_bf16(afr[2][kk], bfr[kk], acc[2], 0,0,0);
        acc[3] = __builtin_amdgcn_mfma_f32_16x16x32_bf16(afr[3][kk], bfr[kk], acc[3], 0,0,0);
      }
      float hv[4];
      #pragma unroll
      for (int q=0;q<4;++q){          // gates: i,f,g,o
        float zi=acc[0][q], zf=acc[1][q], zg=acc[2][q], zo=acc[3][q];
        float cn = sigm(zf)*creg[nt][q] + sigm(zi)*tanh_(zg);
        creg[nt][q] = cn;
        hv[q] = sigm(zo)*tanh_(cn);
      }
      u32 plo, phi;
      asm("v_cvt_pk_bf16_f32 %0, %1, %2" : "=v"(plo) : "v"(hv[0]), "v"(hv[1]));
      asm("v_cvt_pk_bf16_f32 %0, %1, %2" : "=v"(phi) : "v"(hv[2]), "v"(hv[3]));
      uint2 hw; hw.x = plo; hw.y = phi;
      *(uint2*)(lds + bufW + wbB + nt*4096) = hw;
    }
    __syncthreads();
  }
  // fc epilogue: final h in buffer 0; wave handles node-tile nt == wave
  f32x4 fca[4];
  #pragma unroll
  for (int ot=0;ot<4;++ot){ fca[ot][0]=0.f; fca[ot][1]=0.f; fca[ot][2]=0.f; fca[ot][3]=0.f; }
  #pragma unroll
  for (int kk=0;kk<4;++kk){
    bf16x8 b = *(const bf16x8*)(lds + rb[kk] + wave*4096);
    #pragma unroll
    for (int ot=0;ot<4;++ot){
      const float* fr = fc_w + (ot*16 + c16)*128 + kk*32 + g4*8;
      f32x4 wa = *(const f32x4*)fr;
      f32x4 wbv = *(const f32x4*)(fr+4);
      bf16x8 a;
      a[0]=(short)f2bf(wa[0]); a[1]=(short)f2bf(wa[1]);
      a[2]=(short)f2bf(wa[2]); a[3]=(short)f2bf(wa[3]);
      a[4]=(short)f2bf(wbv[0]); a[5]=(short)f2bf(wbv[1]);
      a[6]=(short)f2bf(wbv[2]); a[7]=(short)f2bf(wbv[3]);
      fca[ot] = __builtin_amdgcn_mfma_f32_16x16x32_bf16(a, b, fca[ot], 0,0,0);
    }
  }
  const int node = nb + wave*16 + c16;
  if (node < N_NODES){
    #pragma unroll
    for (int ot=0;ot<4;++ot)
      #pragma unroll
      for (int q=0;q<4;++q){
        int o = ot*16 + g4*4 + q;
        feats[node*64 + o] = fca[ot][q] + fc_b[o];
      }
  }
}

// ---------------------------------------------------------------------------
// RGCN transform-first: tmp[n][r*NO+o] = (relu? h[n]) @ W_r   (K=64, f32)
// block 256 thr, tile 64 nodes x 128 cols; grid (469, 8*NO/128)
// ---------------------------------------------------------------------------
template<int NO, bool RELU>
__global__ __launch_bounds__(256) void transform_kernel(
    const float* __restrict__ h, const float* __restrict__ W,
    float* __restrict__ tmp, int n_nodes)
{
  __shared__ float As[64][68];
  __shared__ float Bs[64][132];
  const int tid = threadIdx.x;
  const int n0 = blockIdx.x*64;
  const int j0 = blockIdx.y*128;
  constexpr int WIDTH = 8*NO;

  for (int idx = tid*4; idx < 4096; idx += 1024){
    int r = idx>>6, c = idx&63;
    int n = n0 + r; if (n > n_nodes-1) n = n_nodes-1;
    f32x4 v = *(const f32x4*)(h + (size_t)n*64 + c);
    if (RELU){
      v[0]=fmaxf(v[0],0.f); v[1]=fmaxf(v[1],0.f);
      v[2]=fmaxf(v[2],0.f); v[3]=fmaxf(v[3],0.f);
    }
    *(f32x4*)&As[r][c] = v;
  }
  for (int idx = tid*4; idx < 8192; idx += 1024){
    int k = idx>>7, j = idx&127;
    int jj = j0 + j;
    int r = jj / NO, o = jj & (NO-1);
    f32x4 v = *(const f32x4*)(W + r*(64*NO) + k*NO + o);
    *(f32x4*)&Bs[k][j] = v;
  }
  __syncthreads();

  const int tx = tid&15, ty = tid>>4;   // 8 cols x 4 nodes per thread
  float acc[4][8];
  #pragma unroll
  for (int i=0;i<4;++i)
    #pragma unroll
    for (int j=0;j<8;++j) acc[i][j]=0.f;

  #pragma unroll 4
  for (int k=0;k<64;++k){
    f32x4 b0 = *(const f32x4*)&Bs[k][tx*8];
    f32x4 b1 = *(const f32x4*)&Bs[k][tx*8+4];
    #pragma unroll
    for (int i=0;i<4;++i){
      float a = As[ty*4+i][k];
      #pragma unroll
      for (int j=0;j<4;++j){
        acc[i][j]   += a*b0[j];
        acc[i][j+4] += a*b1[j];
      }
    }
  }
  #pragma unroll
  for (int i=0;i<4;++i){
    int n = n0 + ty*4 + i;
    if (n < n_nodes){
      *(f32x4*)(tmp + (size_t)n*WIDTH + j0 + tx*8)     = *(f32x4*)&acc[i][0];
      *(f32x4*)(tmp + (size_t)n*WIDTH + j0 + tx*8 + 4) = *(f32x4*)&acc[i][4];
    }
  }
}

// ---------------------------------------------------------------------------
// RGCN scatter: out[dst][:NO] += tmp[src][rel][:NO] * norm   (2-deep pipeline)
// NO=64: wave per edge.  NO=16: 4 edges per wave.
// ---------------------------------------------------------------------------
template<int NO>
__global__ __launch_bounds__(256) void scatter_kernel(
    const float* __restrict__ tmp, const int* __restrict__ src,
    const int* __restrict__ dst, const int* __restrict__ rel,
    const float* __restrict__ enorm, float* __restrict__ out, int n_edges)
{
  constexpr int EPW = 64/NO;
  constexpr int WIDTH = 8*NO;
  const int lane = threadIdx.x & 63;
  const int es = (NO==64) ? 0 : (lane>>4);
  const int o  = lane & (NO-1);
  const long gw = (long)((blockIdx.x*256 + threadIdx.x)>>6);
  const long stride = (long)gridDim.x*4*EPW;
  long e = gw*EPW + es;
  if (e >= n_edges) return;
  int s=src[e], d=dst[e], r=rel[e]; float nm=enorm[e];
  float v = tmp[(size_t)s*WIDTH + r*NO + o];
  while (true){
    long e1 = e + stride;
    bool more = (e1 < n_edges);
    int s1=0,d1=0,r1=0; float nm1=0.f, v1=0.f;
    if (more){
      s1=src[e1]; d1=dst[e1]; r1=rel[e1]; nm1=enorm[e1];
      v1 = tmp[(size_t)s1*WIDTH + r1*NO + o];
    }
    unsafeAtomicAdd(out + (size_t)d*NO + o, v*nm);
    if (!more) break;
    s=s1; d=d1; r=r1; nm=nm1; v=v1; e=e1;
  }
}

// ---------------------------------------------------------------------------
extern "C" void kernel_launch(void* const* d_in, const int* in_sizes, int n_in,
                              void* d_out, int out_size, void* d_ws, size_t ws_size,
                              hipStream_t stream)
{
  const int*   tok    = (const int*)  d_in[0];
  const int*   src    = (const int*)  d_in[2];
  const int*   dst    = (const int*)  d_in[3];
  const int*   rel    = (const int*)  d_in[4];
  const float* enorm  = (const float*)d_in[5];
  const float* emb    = (const float*)d_in[6];
  const float* w_ih   = (const float*)d_in[7];
  const float* w_hh   = (const float*)d_in[8];
  const float* b_ih   = (const float*)d_in[9];
  const float* b_hh   = (const float*)d_in[10];
  const float* fc_w   = (const float*)d_in[11];
  const float* fc_b   = (const float*)d_in[12];
  const float* basis0 = (const float*)d_in[13];
  const float* wcomp0 = (const float*)d_in[14];
  const float* basis1 = (const float*)d_in[15];
  const float* wcomp1 = (const float*)d_in[16];
  const float* basis2 = (const float*)d_in[17];
  const float* wcomp2 = (const float*)d_in[18];

  char* ws = (char*)d_ws;
  // tmp [0, 61.44M) ; eproj overlaps its head (dead before first transform)
  float* tmp   = (float*)(ws);                 // 61,440,000 B
  u16*   eproj = (u16*)  (ws);                 // 10,240,000 B (inside tmp)
  float* feats = (float*)(ws + 61440000);      //  7,680,000 B
  float* g1    = (float*)(ws + 69120000);      //  7,680,000 B
  float* g2    = (float*)(ws + 76800000);      //  7,680,000 B
  float* W0    = (float*)(ws + 84480000);      //    131,072 B
  float* W1    = (float*)(ws + 84611072);      //    131,072 B
  float* W2    = (float*)(ws + 84742144);      //     32,768 B

  wmat_kernel<<<288, 256, 0, stream>>>(basis0, wcomp0, basis1, wcomp1,
                                       basis2, wcomp2, W0, W1, W2);
  embproj_kernel<<<157, 256, 0, stream>>>(emb, w_ih, b_ih, b_hh, eproj);
  lstm_kernel<<<235, 512, 0, stream>>>(tok, eproj, w_hh, fc_w, fc_b, feats);

  // layer 0: feats -> tmp -> g1
  transform_kernel<64,false><<<dim3(469,4), 256, 0, stream>>>(feats, W0, tmp, N_NODES);
  hipMemsetAsync(g1, 0, 30000*64*4, stream);
  scatter_kernel<64><<<2048, 256, 0, stream>>>(tmp, src, dst, rel, enorm, g1, 480000);

  // layer 1: relu(g1) -> tmp -> g2
  transform_kernel<64,true><<<dim3(469,4), 256, 0, stream>>>(g1, W1, tmp, N_NODES);
  hipMemsetAsync(g2, 0, 30000*64*4, stream);
  scatter_kernel<64><<<2048, 256, 0, stream>>>(tmp, src, dst, rel, enorm, g2, 480000);

  // layer 2: relu(g2) -> tmp -> out
  transform_kernel<16,true><<<dim3(469,1), 256, 0, stream>>>(g2, W2, tmp, N_NODES);
  hipMemsetAsync(d_out, 0, 30000*16*4, stream);
  scatter_kernel<16><<<2048, 256, 0, stream>>>(tmp, src, dst, rel, enorm, (float*)d_out, 480000);
}

// Round 5
// 685.427 us; speedup vs baseline: 1.5278x; 1.0742x over previous
//
#include <hip/hip_runtime.h>

typedef float  f32x4  __attribute__((ext_vector_type(4)));
typedef short  bf16x8 __attribute__((ext_vector_type(8)));
typedef unsigned int   u32;
typedef unsigned short u16;

#define N_NODES 30000
#define VOCABSZ 10000
#define LOG2E 1.442695040888963f

__device__ __forceinline__ float sigm(float x){
  return __builtin_amdgcn_rcpf(1.f + __builtin_amdgcn_exp2f(-LOG2E*x));
}
__device__ __forceinline__ float tanh_(float x){
  return 1.f - 2.f*__builtin_amdgcn_rcpf(1.f + __builtin_amdgcn_exp2f((2.f*LOG2E)*x));
}
__device__ __forceinline__ u16 f2bf(float f){   // round-to-nearest-even bf16
  u32 u = __builtin_bit_cast(u32, f);
  u = u + 0x7fffu + ((u>>16)&1u);
  return (u16)(u>>16);
}
__device__ __forceinline__ float bflo(u32 u){ return __builtin_bit_cast(float, u<<16); }
__device__ __forceinline__ float bfhi(u32 u){ return __builtin_bit_cast(float, u & 0xffff0000u); }

// ---------------------------------------------------------------------------
// W_r = sum_b wcomp[r,b] * basis[b]  -> stored [r][i][o] f32 (GEMM-B layout)
// ---------------------------------------------------------------------------
__global__ __launch_bounds__(256) void wmat_kernel(
    const float* __restrict__ b0, const float* __restrict__ c0,
    const float* __restrict__ b1, const float* __restrict__ c1,
    const float* __restrict__ b2, const float* __restrict__ c2,
    float* __restrict__ W0, float* __restrict__ W1, float* __restrict__ W2)
{
  int id = blockIdx.x*256 + threadIdx.x;
  if (id < 32768){
    int r = id>>12;
    float s = 0.f;
    #pragma unroll
    for (int b=0;b<4;++b) s += c0[r*4+b]*b0[b*4096 + (id&4095)];
    W0[id] = s;
  } else if (id < 65536){
    int k = id - 32768;
    int r = k>>12;
    float s = 0.f;
    #pragma unroll
    for (int b=0;b<4;++b) s += c1[r*4+b]*b1[b*4096 + (k&4095)];
    W1[k] = s;
  } else if (id < 73728){
    int k = id - 65536;
    int r = k>>10;
    float s = 0.f;
    #pragma unroll
    for (int b=0;b<4;++b) s += c2[r*4+b]*b2[b*1024 + (k&1023)];
    W2[k] = s;
  }
}

// ---------------------------------------------------------------------------
// emb_proj: bf16 table [v][512] in GATHER-FRIENDLY order:
//   original j = g*128 + w*16 + g4*4 + jl  ->  j' = w*64 + g4*16 + jl*4 + g
// grid (157, 4): blockIdx.y covers 4 of the 16 jt-chunks (occupancy x4).
// ---------------------------------------------------------------------------
__global__ __launch_bounds__(256) void embproj_kernel(
    const float* __restrict__ emb, const float* __restrict__ w_ih,
    const float* __restrict__ b_ih, const float* __restrict__ b_hh,
    u16* __restrict__ eproj)
{
  __shared__ float et[64*132];
  __shared__ float wt[32*132];
  const int tid = threadIdx.x;
  const int v0 = blockIdx.x*64;
  const int vq = tid>>4, jq = tid&15;

  for (int idx = tid*4; idx < 64*128; idx += 1024){
    int row = idx>>7, col = idx&127;
    int vr = v0 + row; if (vr > VOCABSZ-1) vr = VOCABSZ-1;
    *(f32x4*)&et[row*132+col] = *(const f32x4*)&emb[vr*128+col];
  }
  for (int jt = blockIdx.y*4; jt < blockIdx.y*4 + 4; ++jt){
    __syncthreads();
    for (int idx = tid*4; idx < 32*128; idx += 1024){
      int row = idx>>7, col = idx&127;
      *(f32x4*)&wt[row*132+col] = *(const f32x4*)&w_ih[(jt*32+row)*128+col];
    }
    __syncthreads();
    float acc[4][2] = {};
    #pragma unroll 4
    for (int k=0;k<128;++k){
      float w0v = wt[(jq*2+0)*132+k];
      float w1v = wt[(jq*2+1)*132+k];
      #pragma unroll
      for (int a=0;a<4;++a){
        float e = et[(vq*4+a)*132+k];
        acc[a][0] += e*w0v;
        acc[a][1] += e*w1v;
      }
    }
    int jb = jt*32 + jq*2;
    float bi0 = b_ih[jb]   + b_hh[jb];
    float bi1 = b_ih[jb+1] + b_hh[jb+1];
    // j -> j' mapping (jb even => second value lands at j'+4)
    int g  = jb>>7, rem = jb&127;
    int w  = rem>>4, q4 = (rem>>2)&3, jl = rem&3;
    int jp = w*64 + q4*16 + jl*4 + g;
    #pragma unroll
    for (int a=0;a<4;++a){
      int v = v0 + vq*4 + a;
      if (v < VOCABSZ){
        eproj[v*512 + jp]     = f2bf(acc[a][0]+bi0);
        eproj[v*512 + jp + 4] = f2bf(acc[a][1]+bi1);
      }
    }
  }
}

// ---------------------------------------------------------------------------
// Fused 32-step reverse LSTM + fc epilogue.  64 nodes/block, 8 waves, grid 469.
// LDS = 32KB h-dbuf + 4.2KB u16 tokens  ->  2 blocks/CU = 4 waves/SIMD.
// Wave w owns j-slice [16w,16w+16) of all 4 gates; w_hh A-frags in registers;
// h (bf16, XOR-swizzled) streams via LDS; rolling full-step gather prefetch.
// ---------------------------------------------------------------------------
__global__ __launch_bounds__(512, 2) void lstm_kernel(
    const int* __restrict__ tok, const u16* __restrict__ eproj,
    const float* __restrict__ w_hh, const float* __restrict__ fc_w,
    const float* __restrict__ fc_b, float* __restrict__ feats)
{
  __shared__ __align__(16) char lds[32768];
  __shared__ u16 tokL[64*33];
  const int tid = threadIdx.x;
  const int wave = tid>>6, lane = tid&63;
  const int c16 = lane&15, g4 = lane>>4;
  const int nb = blockIdx.x*64;

  // persistent w_hh A-fragments: j = g*128 + wave*16 + c16 ; k = kk*32+8*g4+i
  bf16x8 afr[4][4];
  #pragma unroll
  for (int g=0; g<4; ++g){
    const float* wr = w_hh + (g*128 + wave*16 + c16)*128 + g4*8;
    #pragma unroll
    for (int kk=0; kk<4; ++kk){
      f32x4 wa = *(const f32x4*)(wr + kk*32);
      f32x4 wbv = *(const f32x4*)(wr + kk*32 + 4);
      bf16x8 a;
      a[0]=(short)f2bf(wa[0]); a[1]=(short)f2bf(wa[1]);
      a[2]=(short)f2bf(wa[2]); a[3]=(short)f2bf(wa[3]);
      a[4]=(short)f2bf(wbv[0]); a[5]=(short)f2bf(wbv[1]);
      a[6]=(short)f2bf(wbv[2]); a[7]=(short)f2bf(wbv[3]);
      afr[g][kk] = a;
    }
  }
  { // zero h buffer 0 (16KB)
    f32x4 z = {0.f,0.f,0.f,0.f};
    for (int i = tid*16; i < 16384; i += 8192) *(f32x4*)(lds + i) = z;
  }
  { // stage tokens as u16: tokL[n][33] (padded)
    int n = tid>>3, t0 = (tid&7)*4;
    int node = nb + n; if (node > N_NODES-1) node = N_NODES-1;
    int4 a = *(const int4*)(tok + node*32 + t0);
    tokL[n*33 + t0    ] = (u16)a.x;
    tokL[n*33 + t0 + 1] = (u16)a.y;
    tokL[n*33 + t0 + 2] = (u16)a.z;
    tokL[n*33 + t0 + 3] = (u16)a.w;
  }
  const int swz = (c16&7)<<4;
  int rb[4];
  #pragma unroll
  for (int kk=0;kk<4;++kk) rb[kk] = c16*256 + ((kk*64 + g4*16)^swz);
  const int wbB = c16*256 + ((wave*32 + g4*8)^swz);

  float creg[4][4];
  #pragma unroll
  for (int nt=0;nt<4;++nt)
    #pragma unroll
    for (int q=0;q<4;++q) creg[nt][q]=0.f;

  __syncthreads();

  const size_t gbase = (size_t)(wave*128 + g4*32);
  uint4 gxX[4], gxY[4];
  #pragma unroll
  for (int nt=0;nt<4;++nt){                 // initial gathers (t=0, t'=31)
    int ptok = tokL[(nt*16+c16)*33 + 31];
    const char* ep = (const char*)eproj + (size_t)ptok*1024 + gbase;
    gxX[nt] = *(const uint4*)ep;
    gxY[nt] = *(const uint4*)(ep+16);
  }

  for (int t=0; t<32; ++t){
    const int bufR = (t&1)<<14, bufW = bufR ^ 16384;
    int ptk[4];
    if (t < 31){
      #pragma unroll
      for (int nt=0;nt<4;++nt) ptk[nt] = tokL[(nt*16+c16)*33 + 30 - t];
    }
    #pragma unroll
    for (int nt=0; nt<4; ++nt){
      uint4 X = gxX[nt], Y = gxY[nt];
      f32x4 acc[4];
      acc[0][0]=bflo(X.x); acc[1][0]=bfhi(X.x); acc[2][0]=bflo(X.y); acc[3][0]=bfhi(X.y);
      acc[0][1]=bflo(X.z); acc[1][1]=bfhi(X.z); acc[2][1]=bflo(X.w); acc[3][1]=bfhi(X.w);
      acc[0][2]=bflo(Y.x); acc[1][2]=bfhi(Y.x); acc[2][2]=bflo(Y.y); acc[3][2]=bfhi(Y.y);
      acc[0][3]=bflo(Y.z); acc[1][3]=bfhi(Y.z); acc[2][3]=bflo(Y.w); acc[3][3]=bfhi(Y.w);
      if (t < 31){                          // rolling prefetch: next step, same nt
        const char* ep = (const char*)eproj + (size_t)ptk[nt]*1024 + gbase;
        gxX[nt] = *(const uint4*)ep;
        gxY[nt] = *(const uint4*)(ep+16);
      }
      bf16x8 bfr[4];
      #pragma unroll
      for (int kk=0;kk<4;++kk)
        bfr[kk] = *(const bf16x8*)(lds + bufR + rb[kk] + nt*4096);
      #pragma unroll
      for (int kk=0;kk<4;++kk){
        acc[0] = __builtin_amdgcn_mfma_f32_16x16x32_bf16(afr[0][kk], bfr[kk], acc[0], 0,0,0);
        acc[1] = __builtin_amdgcn_mfma_f32_16x16x32_bf16(afr[1][kk], bfr[kk], acc[1], 0,0,0);
        acc[2] = __builtin_amdgcn_mfma_f32_16x16x32_bf16(afr[2][kk], bfr[kk], acc[2], 0,0,0);
        acc[3] = __builtin_amdgcn_mfma_f32_16x16x32_bf16(afr[3][kk], bfr[kk], acc[3], 0,0,0);
      }
      float hv[4];
      #pragma unroll
      for (int q=0;q<4;++q){          // gates: i,f,g,o
        float zi=acc[0][q], zf=acc[1][q], zg=acc[2][q], zo=acc[3][q];
        float cn = sigm(zf)*creg[nt][q] + sigm(zi)*tanh_(zg);
        creg[nt][q] = cn;
        hv[q] = sigm(zo)*tanh_(cn);
      }
      u32 plo, phi;
      asm("v_cvt_pk_bf16_f32 %0, %1, %2" : "=v"(plo) : "v"(hv[0]), "v"(hv[1]));
      asm("v_cvt_pk_bf16_f32 %0, %1, %2" : "=v"(phi) : "v"(hv[2]), "v"(hv[3]));
      uint2 hw; hw.x = plo; hw.y = phi;
      *(uint2*)(lds + bufW + wbB + nt*4096) = hw;
    }
    __syncthreads();
  }
  // fc epilogue: final h in buffer 0; wave pair handles node-tile wave>>1,
  // each half covers 2 of the 4 output tiles.
  const int w2 = wave>>1, half = wave&1;
  f32x4 fca[2];
  #pragma unroll
  for (int oi=0;oi<2;++oi){ fca[oi][0]=0.f; fca[oi][1]=0.f; fca[oi][2]=0.f; fca[oi][3]=0.f; }
  #pragma unroll
  for (int kk=0;kk<4;++kk){
    bf16x8 b = *(const bf16x8*)(lds + rb[kk] + w2*4096);
    #pragma unroll
    for (int oi=0;oi<2;++oi){
      int ot = half*2 + oi;
      const float* fr = fc_w + (ot*16 + c16)*128 + kk*32 + g4*8;
      f32x4 wa = *(const f32x4*)fr;
      f32x4 wbv = *(const f32x4*)(fr+4);
      bf16x8 a;
      a[0]=(short)f2bf(wa[0]); a[1]=(short)f2bf(wa[1]);
      a[2]=(short)f2bf(wa[2]); a[3]=(short)f2bf(wa[3]);
      a[4]=(short)f2bf(wbv[0]); a[5]=(short)f2bf(wbv[1]);
      a[6]=(short)f2bf(wbv[2]); a[7]=(short)f2bf(wbv[3]);
      fca[oi] = __builtin_amdgcn_mfma_f32_16x16x32_bf16(a, b, fca[oi], 0,0,0);
    }
  }
  const int node = nb + w2*16 + c16;
  if (node < N_NODES){
    #pragma unroll
    for (int oi=0;oi<2;++oi)
      #pragma unroll
      for (int q=0;q<4;++q){
        int o = (half*2+oi)*16 + g4*4 + q;
        feats[node*64 + o] = fca[oi][q] + fc_b[o];
      }
  }
}

// ---------------------------------------------------------------------------
// RGCN transform-first: tmp[n][r*NO+o] = (relu? h[n]) @ W_r   (K=64, f32)
// block 256 thr, tile 64 nodes x 128 cols; grid (469, 8*NO/128)
// ---------------------------------------------------------------------------
template<int NO, bool RELU>
__global__ __launch_bounds__(256) void transform_kernel(
    const float* __restrict__ h, const float* __restrict__ W,
    float* __restrict__ tmp, int n_nodes)
{
  __shared__ float As[64][68];
  __shared__ float Bs[64][132];
  const int tid = threadIdx.x;
  const int n0 = blockIdx.x*64;
  const int j0 = blockIdx.y*128;
  constexpr int WIDTH = 8*NO;

  for (int idx = tid*4; idx < 4096; idx += 1024){
    int r = idx>>6, c = idx&63;
    int n = n0 + r; if (n > n_nodes-1) n = n_nodes-1;
    f32x4 v = *(const f32x4*)(h + (size_t)n*64 + c);
    if (RELU){
      v[0]=fmaxf(v[0],0.f); v[1]=fmaxf(v[1],0.f);
      v[2]=fmaxf(v[2],0.f); v[3]=fmaxf(v[3],0.f);
    }
    *(f32x4*)&As[r][c] = v;
  }
  for (int idx = tid*4; idx < 8192; idx += 1024){
    int k = idx>>7, j = idx&127;
    int jj = j0 + j;
    int r = jj / NO, o = jj & (NO-1);
    f32x4 v = *(const f32x4*)(W + r*(64*NO) + k*NO + o);
    *(f32x4*)&Bs[k][j] = v;
  }
  __syncthreads();

  const int tx = tid&15, ty = tid>>4;   // 8 cols x 4 nodes per thread
  float acc[4][8];
  #pragma unroll
  for (int i=0;i<4;++i)
    #pragma unroll
    for (int j=0;j<8;++j) acc[i][j]=0.f;

  #pragma unroll 4
  for (int k=0;k<64;++k){
    f32x4 b0 = *(const f32x4*)&Bs[k][tx*8];
    f32x4 b1 = *(const f32x4*)&Bs[k][tx*8+4];
    #pragma unroll
    for (int i=0;i<4;++i){
      float a = As[ty*4+i][k];
      #pragma unroll
      for (int j=0;j<4;++j){
        acc[i][j]   += a*b0[j];
        acc[i][j+4] += a*b1[j];
      }
    }
  }
  #pragma unroll
  for (int i=0;i<4;++i){
    int n = n0 + ty*4 + i;
    if (n < n_nodes){
      *(f32x4*)(tmp + (size_t)n*WIDTH + j0 + tx*8)     = *(f32x4*)&acc[i][0];
      *(f32x4*)(tmp + (size_t)n*WIDTH + j0 + tx*8 + 4) = *(f32x4*)&acc[i][4];
    }
  }
}

// ---------------------------------------------------------------------------
// RGCN scatter: out[dst][:NO] += tmp[src][rel][:NO] * norm   (2-deep pipeline)
// NO=64: wave per edge.  NO=16: 4 edges per wave.
// ---------------------------------------------------------------------------
template<int NO>
__global__ __launch_bounds__(256) void scatter_kernel(
    const float* __restrict__ tmp, const int* __restrict__ src,
    const int* __restrict__ dst, const int* __restrict__ rel,
    const float* __restrict__ enorm, float* __restrict__ out, int n_edges)
{
  constexpr int EPW = 64/NO;
  constexpr int WIDTH = 8*NO;
  const int lane = threadIdx.x & 63;
  const int es = (NO==64) ? 0 : (lane>>4);
  const int o  = lane & (NO-1);
  const long gw = (long)((blockIdx.x*256 + threadIdx.x)>>6);
  const long stride = (long)gridDim.x*4*EPW;
  long e = gw*EPW + es;
  if (e >= n_edges) return;
  int s=src[e], d=dst[e], r=rel[e]; float nm=enorm[e];
  float v = tmp[(size_t)s*WIDTH + r*NO + o];
  while (true){
    long e1 = e + stride;
    bool more = (e1 < n_edges);
    int s1=0,d1=0,r1=0; float nm1=0.f, v1=0.f;
    if (more){
      s1=src[e1]; d1=dst[e1]; r1=rel[e1]; nm1=enorm[e1];
      v1 = tmp[(size_t)s1*WIDTH + r1*NO + o];
    }
    unsafeAtomicAdd(out + (size_t)d*NO + o, v*nm);
    if (!more) break;
    s=s1; d=d1; r=r1; nm=nm1; v=v1; e=e1;
  }
}

// ---------------------------------------------------------------------------
extern "C" void kernel_launch(void* const* d_in, const int* in_sizes, int n_in,
                              void* d_out, int out_size, void* d_ws, size_t ws_size,
                              hipStream_t stream)
{
  const int*   tok    = (const int*)  d_in[0];
  const int*   src    = (const int*)  d_in[2];
  const int*   dst    = (const int*)  d_in[3];
  const int*   rel    = (const int*)  d_in[4];
  const float* enorm  = (const float*)d_in[5];
  const float* emb    = (const float*)d_in[6];
  const float* w_ih   = (const float*)d_in[7];
  const float* w_hh   = (const float*)d_in[8];
  const float* b_ih   = (const float*)d_in[9];
  const float* b_hh   = (const float*)d_in[10];
  const float* fc_w   = (const float*)d_in[11];
  const float* fc_b   = (const float*)d_in[12];
  const float* basis0 = (const float*)d_in[13];
  const float* wcomp0 = (const float*)d_in[14];
  const float* basis1 = (const float*)d_in[15];
  const float* wcomp1 = (const float*)d_in[16];
  const float* basis2 = (const float*)d_in[17];
  const float* wcomp2 = (const float*)d_in[18];

  char* ws = (char*)d_ws;
  // tmp [0, 61.44M) ; eproj overlaps its head (dead before first transform)
  float* tmp   = (float*)(ws);                 // 61,440,000 B
  u16*   eproj = (u16*)  (ws);                 // 10,240,000 B (inside tmp)
  float* feats = (float*)(ws + 61440000);      //  7,680,000 B
  float* g1    = (float*)(ws + 69120000);      //  7,680,000 B
  float* g2    = (float*)(ws + 76800000);      //  7,680,000 B (adjacent to g1)
  float* W0    = (float*)(ws + 84480000);      //    131,072 B
  float* W1    = (float*)(ws + 84611072);      //    131,072 B
  float* W2    = (float*)(ws + 84742144);      //     32,768 B

  wmat_kernel<<<288, 256, 0, stream>>>(basis0, wcomp0, basis1, wcomp1,
                                       basis2, wcomp2, W0, W1, W2);
  embproj_kernel<<<dim3(157,4), 256, 0, stream>>>(emb, w_ih, b_ih, b_hh, eproj);

  // zero all atomic targets up-front (g1+g2 contiguous -> one memset)
  hipMemsetAsync(g1, 0, 15360000, stream);
  hipMemsetAsync(d_out, 0, 30000*16*4, stream);

  lstm_kernel<<<469, 512, 0, stream>>>(tok, eproj, w_hh, fc_w, fc_b, feats);

  // layer 0: feats -> tmp -> g1
  transform_kernel<64,false><<<dim3(469,4), 256, 0, stream>>>(feats, W0, tmp, N_NODES);
  scatter_kernel<64><<<2048, 256, 0, stream>>>(tmp, src, dst, rel, enorm, g1, 480000);

  // layer 1: relu(g1) -> tmp -> g2
  transform_kernel<64,true><<<dim3(469,4), 256, 0, stream>>>(g1, W1, tmp, N_NODES);
  scatter_kernel<64><<<2048, 256, 0, stream>>>(tmp, src, dst, rel, enorm, g2, 480000);

  // layer 2: relu(g2) -> tmp -> out
  transform_kernel<16,true><<<dim3(469,1), 256, 0, stream>>>(g2, W2, tmp, N_NODES);
  scatter_kernel<16><<<2048, 256, 0, stream>>>(tmp, src, dst, rel, enorm, (float*)d_out, 480000);
}